// Round 1
// baseline (99.018 us; speedup 1.0000x reference)
//
#include <hip/hip_runtime.h>
#include <math.h>

// SOPTD RHS: two tiny MLPs + scalar 2nd-order ODE arithmetic.
// Single wave (64 lanes). Lane j (mod 32) owns neuron j of each 32-wide
// layer. Activations stay in registers; cross-neuron data moves via __shfl
// (wave64-synchronous -> no __syncthreads, no LDS). All weights preloaded
// up-front so the one HBM latency is paid once, before the serial chain.

__global__ __launch_bounds__(64) void soptd_kernel(
    const float* __restrict__ states,
    const float* __restrict__ W1, const float* __restrict__ b1,
    const float* __restrict__ W2, const float* __restrict__ b2,
    const float* __restrict__ W3, const float* __restrict__ b3,
    const float* __restrict__ W4, const float* __restrict__ b4,
    const float* __restrict__ W5, const float* __restrict__ b5,
    const float* __restrict__ W6, const float* __restrict__ b6,
    const float* __restrict__ W7, const float* __restrict__ b7,
    const float* __restrict__ W8, const float* __restrict__ b8,
    const float* __restrict__ Kp1, const float* __restrict__ Kp2,
    const float* __restrict__ Tau1, const float* __restrict__ Tau2,
    const float* __restrict__ z1, const float* __restrict__ z2,
    float* __restrict__ out)
{
    const int j  = threadIdx.x;   // 0..63 (one wave)
    const int jj = j & 31;        // neuron index for 32-wide layers
    const int j4 = j & 3;         // neuron index for the 4-wide layer

    // ---------- preload: everything independent of activations ----------
    float w2c[4];
#pragma unroll
    for (int k = 0; k < 4; ++k)  w2c[k] = W2[k*32 + jj];
    float w3c[32];
#pragma unroll
    for (int k = 0; k < 32; ++k) w3c[k] = W3[k*32 + jj];
    float w5c[5];
#pragma unroll
    for (int k = 0; k < 5; ++k)  w5c[k] = W5[k*32 + jj];
    float w6c[32];
#pragma unroll
    for (int k = 0; k < 32; ++k) w6c[k] = W6[k*32 + jj];
    float w7c[32];
#pragma unroll
    for (int k = 0; k < 32; ++k) w7c[k] = W7[k*32 + jj];
    const float w4r0 = W4[jj*2 + 0];
    const float w4r1 = W4[jj*2 + 1];
    float w8r[4];
#pragma unroll
    for (int c = 0; c < 4; ++c)  w8r[c] = W8[jj*4 + c];

    const float bb2 = b2[jj], bb3 = b3[jj];
    const float bb5 = b5[jj], bb6 = b6[jj], bb7 = b7[jj];
    const float b1j = b1[j4];
    const float w1_0 = W1[0*4 + j4], w1_1 = W1[1*4 + j4], w1_2 = W1[2*4 + j4];
    const float b40 = b4[0], b41 = b4[1];
    const float b80 = b8[0], b81 = b8[1], b82 = b8[2], b83 = b8[3];

    const float u    = states[0];
    const float x1   = states[1];
    const float x2   = states[2];
    const float x1p  = states[3];
    const float x2p  = states[4];

    const float kp1  = Kp1[0],  kp2  = Kp2[0];
    const float tau1 = Tau1[0], tau2 = Tau2[0];
    const float zz1  = z1[0],   zz2  = z2[0];

    // ---------- MLP 1: [u,x1,x2] -> 4 (linear) ----------
    float h1 = b1j + u*w1_0 + x1*w1_1 + x2*w1_2;   // valid on lanes 0..3

    // 4 -> 32, tanh
    float a = bb2;
#pragma unroll
    for (int k = 0; k < 4; ++k) a += __shfl(h1, k) * w2c[k];
    float h = tanhf(a);

    // 32 -> 32, tanh
    a = bb3;
#pragma unroll
    for (int k = 0; k < 32; ++k) a += __shfl(h, k) * w3c[k];
    h = tanhf(a);

    // 32 -> 2 (linear): butterfly reduce; mask duplicate upper half-wave
    float p0 = (j < 32) ? h * w4r0 : 0.0f;
    float p1 = (j < 32) ? h * w4r1 : 0.0f;
#pragma unroll
    for (int off = 32; off >= 1; off >>= 1) {
        p0 += __shfl_xor(p0, off);
        p1 += __shfl_xor(p1, off);
    }
    const float u60 = p0 + b40;
    const float u61 = p1 + b41;

    // ---------- scalar ODE arithmetic (every lane, redundantly) ----------
    const float x1pd = (kp1/tau1*u60 - 2.0f*(zz1*x1) - x1p/tau1) / tau1;
    const float x2pd = (kp2/tau2*u61 - 2.0f*(zz2*x2) - x2p/tau2) / tau2;
    // x_dot = {x1p, x2p, x1pd, x2pd, u} -- in registers on EVERY lane

    // ---------- MLP 2: 5 -> 32 (linear); no shuffle needed ----------
    float g = bb5 + x1p*w5c[0] + x2p*w5c[1] + x1pd*w5c[2] + x2pd*w5c[3]
                  + u*w5c[4];

    // 32 -> 32, tanh
    a = bb6;
#pragma unroll
    for (int k = 0; k < 32; ++k) a += __shfl(g, k) * w6c[k];
    g = tanhf(a);

    // 32 -> 32, tanh
    a = bb7;
#pragma unroll
    for (int k = 0; k < 32; ++k) a += __shfl(g, k) * w7c[k];
    g = tanhf(a);

    // 32 -> 4 (linear): 4 butterfly reductions
    float q0 = (j < 32) ? g * w8r[0] : 0.0f;
    float q1 = (j < 32) ? g * w8r[1] : 0.0f;
    float q2 = (j < 32) ? g * w8r[2] : 0.0f;
    float q3 = (j < 32) ? g * w8r[3] : 0.0f;
#pragma unroll
    for (int off = 32; off >= 1; off >>= 1) {
        q0 += __shfl_xor(q0, off);
        q1 += __shfl_xor(q1, off);
        q2 += __shfl_xor(q2, off);
        q3 += __shfl_xor(q3, off);
    }

    if (j == 0) {
        out[0] = 0.0f;           // u_dot = 0 (d_out is poisoned, must write)
        out[1] = q0 + b80;
        out[2] = q1 + b81;
        out[3] = q2 + b82;
        out[4] = q3 + b83;
    }
}

extern "C" void kernel_launch(void* const* d_in, const int* in_sizes, int n_in,
                              void* d_out, int out_size, void* d_ws, size_t ws_size,
                              hipStream_t stream) {
    // d_in order: t, states, W1,b1, W2,b2, W3,b3, W4,b4,
    //             W5,b5, W6,b6, W7,b7, W8,b8, Kp1,Kp2,Tau1,Tau2,z1,z2
    const float* states = (const float*)d_in[1];
    const float* W1 = (const float*)d_in[2];  const float* b1 = (const float*)d_in[3];
    const float* W2 = (const float*)d_in[4];  const float* b2 = (const float*)d_in[5];
    const float* W3 = (const float*)d_in[6];  const float* b3 = (const float*)d_in[7];
    const float* W4 = (const float*)d_in[8];  const float* b4 = (const float*)d_in[9];
    const float* W5 = (const float*)d_in[10]; const float* b5 = (const float*)d_in[11];
    const float* W6 = (const float*)d_in[12]; const float* b6 = (const float*)d_in[13];
    const float* W7 = (const float*)d_in[14]; const float* b7 = (const float*)d_in[15];
    const float* W8 = (const float*)d_in[16]; const float* b8 = (const float*)d_in[17];
    const float* Kp1  = (const float*)d_in[18];
    const float* Kp2  = (const float*)d_in[19];
    const float* Tau1 = (const float*)d_in[20];
    const float* Tau2 = (const float*)d_in[21];
    const float* z1   = (const float*)d_in[22];
    const float* z2   = (const float*)d_in[23];

    soptd_kernel<<<dim3(1), dim3(64), 0, stream>>>(
        states, W1, b1, W2, b2, W3, b3, W4, b4,
        W5, b5, W6, b6, W7, b7, W8, b8,
        Kp1, Kp2, Tau1, Tau2, z1, z2, (float*)d_out);
}